// Round 8
// baseline (2696.698 us; speedup 1.0000x reference)
//
#include <hip/hip_runtime.h>
#include <cstddef>

// SimpleLSTM: B=64, D=512, T=512, H=1024, O=1 — fp16, tagged h-packets,
// INTRA-XCD GROUPS: 8 groups x 32 blocks x 8 batches, group g pinned to XCD g
// (32 blocks = 32 CUs = one XCD). ALL h-exchange is XCD-local.
// MODEL (r2-r6): time = 512 x serial coherence chain; legs & placement matter,
// bytes don't (r5). r4: partial XCD locality (8->2) cut 25%. r6: packet fusion
// (publish=1 store, poll=data load) cut 23%. This round: full locality (2->1)
// + 8 independent recurrences (no cross-group coupling) + all-8-wave reduce.
// Per block: 32 j x 4 gates x 8 batches; K=1536 split 8 waves; 48 A-frags/wave
// (~192 regs — enabled by fixing launch_bounds 2->1; residency was 1 blk/CU
// all along). B-frag batch dim half-duplicated (cols 8-15 = cols 0-7, ignored).
// Safety induction unchanged: publish(t+1) <= own barrier(t) <= all 8 waves
// validated tag t; reader wave of block r' is w=r'>>2, whose validate covers r'.
// ws layout (ends at 46,661,632 = proven bound):
//   [0, 32MB)            xT: f16 [T=512][B=64][D=512]
//   [32MB, +12.58MB)     Wf: f16 A-frags [r=32][ks=48][mt=8][lane=64][8]
//                        (reused after weight load as out-partials
//                         part[t=512][g=8][r=32][b8=8] f32 = 4MB, atomicAdd'd)
//   [46,137,344, +512KB) pkt[parity=2][g=8][r=32][mt=8][b=8] x 16B packets
//                        packet = {h0,h1,h2,tagA | h3,tagB,pad,pad} (2 u64)
//                        claim/ready ctrs overlay first ~1KB of parity-1 region
//                        (overwritten by block (0,0..1)'s step-0 publish; their
//                        stale tag bits are 0 != 1 so consumers retry — safe).
#define WS_XT_OFF   0ull
#define WS_WF_OFF   33554432ull
#define WS_PK_OFF   46137344ull

typedef _Float16 f16x8 __attribute__((ext_vector_type(8)));
typedef float    f32x4 __attribute__((ext_vector_type(4)));
typedef unsigned short u16;
typedef unsigned int   u32;
typedef unsigned long long u64;

__device__ __forceinline__ u16 f2h(float f) {
  _Float16 h = (_Float16)f;                     // v_cvt_f16_f32, RNE
  return __builtin_bit_cast(u16, h);
}
// Fast gate math: v_exp + v_rcp. Robust at extremes.
__device__ __forceinline__ float sigm(float x) {
  return __builtin_amdgcn_rcpf(1.0f + __expf(-x));
}
__device__ __forceinline__ float tanh_fast(float x) {
  return 1.0f - 2.0f * __builtin_amdgcn_rcpf(__expf(2.0f * x) + 1.0f);
}

// ---------- K0: zero packet region (tags=0 == step-0 expectation, h=0) ----------
__global__ __launch_bounds__(256) void k_init(uint4* pkt16) {
  int t = blockIdx.x * 256 + threadIdx.x;       // 32768 threads x 16B = 512KB
  pkt16[t] = uint4{0u, 0u, 0u, 0u};
}

// ---------- K1: x (B,D,T) f32 -> xT[t][b][d] f16 ----------
__global__ __launch_bounds__(256) void k_xpose(const float* __restrict__ x,
                                               u16* __restrict__ xT) {
  __shared__ float lds[64][65];
  const int d0 = blockIdx.x * 64, t0 = blockIdx.y * 64, b = blockIdx.z;
  const int tid = threadIdx.x;
  const int tt = tid & 63, dr = tid >> 6;
  const float* xp = x + ((size_t)b * 512 + d0) * 512 + t0 + tt;
#pragma unroll
  for (int i = 0; i < 16; ++i) {
    int dd = i * 4 + dr;
    lds[dd][tt] = xp[(size_t)dd * 512];
  }
  __syncthreads();
  const int dp = tid & 31, rr = tid >> 5;
#pragma unroll
  for (int i = 0; i < 8; ++i) {
    int tt2 = i * 8 + rr;
    u32 lo = f2h(lds[dp * 2][tt2]);
    u32 hi = f2h(lds[dp * 2 + 1][tt2]);
    *(u32*)(xT + ((size_t)(t0 + tt2) * 64 + b) * 512 + d0 + dp * 2) = lo | (hi << 16);
  }
}

// ---------- K2: pack [W_ih | W_hh] rows into per-lane MFMA A-fragments (f16) ----------
// chunk c = ((r*48 + ks)*8 + mt) ; within-tile row m: gate=m&3, j=r*32+mt*4+(m>>2)
__global__ __launch_bounds__(256) void k_wfrag(const float* __restrict__ W_ih,
                                               const float* __restrict__ W_hh,
                                               u16* __restrict__ Wf) {
  int gidx = blockIdx.x * 256 + threadIdx.x;    // 786432 threads
  int lane = gidx & 63;
  int c  = gidx >> 6;                           // [0, 12288)
  int mt = c & 7;
  int cc = c >> 3;
  int ks = cc % 48;
  int r  = cc / 48;                             // [0, 32)
  int m = lane & 15, q = lane >> 4;
  int gate = m & 3;
  int j = r * 32 + mt * 4 + (m >> 2);
  int row = gate * 1024 + j;
  const float* src = (ks < 16) ? (W_ih + (size_t)row * 512 + ks * 32 + q * 8)
                               : (W_hh + (size_t)row * 1024 + (ks - 16) * 32 + q * 8);
  union { u16 s[8]; uint4 v; } U;
#pragma unroll
  for (int i = 0; i < 8; ++i) U.s[i] = f2h(src[i]);
  *(uint4*)(Wf + ((size_t)c * 64 + lane) * 8) = U.v;
}

// ---------- K3: persistent cooperative recurrence ----------
// grid 256 = 8 groups x 32 blocks; block 512 = 8 waves; 1 block/CU.
// XCD CLAIM: g = own XCD, r = claimed slot [0,32); overflow probes next XCD
// (correct under any dispatch; exact 32/XCD when 1 block/CU holds).
// Wave w: x K-slices {2w, 2w+1}; h K-slices {4w..4w+4} => producers r'=4w..4w+4,
// packets (r', mt'=2q,2q+1, b=n&7). ALL waves reduce: wave w owns mt-tile w
// (j = r*32 + w*4 + q, all 4 gates, batch n&7; lanes n>=8 duplicate, excluded
// from publish/part). Publish: lanes q==0 & n<8 fire {h0,h1,h2,tagA|h3,tagB}.
__global__ __launch_bounds__(512, 1) void k_lstm(
    const u16* __restrict__ xT, const u16* __restrict__ Wf,
    u64* pkt,
    const float* __restrict__ b_ih, const float* __restrict__ b_hh,
    const float* __restrict__ W_out, float* __restrict__ part) {
  __shared__ f32x4 red[2][8 * 8 * 64];    // [parity][wave][mt][lane], 128 KB
  __shared__ u32 sh_as;                   // claimed (xcd<<8)|slot
  const int tid = threadIdx.x;
  const int w = tid >> 6, lane = tid & 63;

  // claim/ready overlay in parity-1 region (stale bits read as tag 0 -> safe)
  u32* cc = (u32*)(pkt + 32768);

  if (tid == 0) {
    u32 xcc;
    asm volatile("s_getreg_b32 %0, hwreg(HW_REG_XCC_ID)" : "=s"(xcc));
    xcc &= 7u;
    u32 sel = 0u, slot = 0u;
    for (int i = 0; i < 8; ++i) {
      u32 x = (xcc + (u32)i) & 7u;
      u32 s = __hip_atomic_fetch_add(cc + x * 32, 1u,
                                     __ATOMIC_RELAXED, __HIP_MEMORY_SCOPE_AGENT);
      if (s < 32u) { sel = x; slot = s; break; }
    }
    sh_as = (sel << 8) | slot;
  }
  __syncthreads();
  const u32 as = sh_as;
  const int g = (int)(as >> 8);           // group == XCD
  const int r = (int)(as & 255u);         // [0, 32)
  const int bg0 = g * 8, j0 = r * 32;
  const int n = lane & 15, q = lane >> 4;
  const int b8 = n & 7;

  // Step-invariant weights -> registers (unified VGPR/AGPR file)
  f16x8 wfr[6][8];
#pragma unroll
  for (int kl = 0; kl < 6; ++kl) {
    int ks = (kl < 2) ? (2 * w + kl) : (16 + 4 * w + (kl - 2));
#pragma unroll
    for (int mt = 0; mt < 8; ++mt) {
      size_t c = ((size_t)r * 48 + ks) * 8 + mt;
      wfr[kl][mt] = *(const f16x8*)(Wf + (c * 64 + lane) * 8);
    }
  }

  // biases/wout for this wave's tile (j = j0 + w*4 + q), all waves reduce
  float bias0, bias1, bias2, bias3, wout;
  {
    int j = j0 + w * 4 + q;
    bias0 = b_ih[j]        + b_hh[j];
    bias1 = b_ih[1024 + j] + b_hh[1024 + j];
    bias2 = b_ih[2048 + j] + b_hh[2048 + j];
    bias3 = b_ih[3072 + j] + b_hh[3072 + j];
    wout  = W_out[j];
  }

  // Consumer packet bases (u64 units within a parity):
  // idx = (((g*32 + r')*8 + mt')*8 + b)*2 ; per kl: mt'=2q at +0, 2q+1 at +16
  size_t cb[4];
#pragma unroll
  for (int kl = 0; kl < 4; ++kl) {
    int rp = 4 * w + kl;
    cb[kl] = ((((size_t)g * 32 + rp) * 8 + (size_t)(2 * q)) * 8 + b8) * 2;
  }
  // Producer packet base (lane q==0, n<8): (r, mt=w, b=n)
  const size_t pwb = ((((size_t)g * 32 + r) * 8 + w) * 8 + b8) * 2;

  // One-time grid barrier: all Wf loads done before part[] overwrites Wf.
  __syncthreads();                        // drains vmcnt -> wfr in regs
  if (tid == 0) {
    __hip_atomic_fetch_add(cc + 256, 1u, __ATOMIC_RELAXED, __HIP_MEMORY_SCOPE_AGENT);
    while (__hip_atomic_load(cc + 256, __ATOMIC_RELAXED, __HIP_MEMORY_SCOPE_AGENT) < 256u)
      __builtin_amdgcn_s_sleep(8);
  }
  __syncthreads();
  // zero own out-partial slice part[t=tid][g][r][0..8)
  {
    f32x4 z = {0.f, 0.f, 0.f, 0.f};
    f32x4* p4 = (f32x4*)&part[(((size_t)tid * 8 + g) * 32 + r) * 8];
    p4[0] = z; p4[1] = z;
  }
  __syncthreads();                        // drain zero stores before any atomicAdd
  asm volatile("" ::: "memory");

  float c_state = 0.f;
  const f32x4 zero = {0.f, 0.f, 0.f, 0.f};

  for (int t = 0; t < 512; ++t) {
    const u16* xtb = xT + (size_t)t * 32768;

    // flag-independent x loads first (ks = 2w, 2w+1)
    f16x8 bfr[6];
#pragma unroll
    for (int kl = 0; kl < 2; ++kl)
      bfr[kl] = *(const f16x8*)(xtb + (bg0 + b8) * 512 + (2 * w + kl) * 32 + q * 8);

    // x-part MFMAs BEFORE the packet wait: overlap with h propagation
    f32x4 acc[8];
#pragma unroll
    for (int mt = 0; mt < 8; ++mt)
      acc[mt] = __builtin_amdgcn_mfma_f32_16x16x32_f16(wfr[0][mt], bfr[0], zero, 0, 0, 0);
#pragma unroll
    for (int mt = 0; mt < 8; ++mt)
      acc[mt] = __builtin_amdgcn_mfma_f32_16x16x32_f16(wfr[1][mt], bfr[1], acc[mt], 0, 0, 0);
#pragma unroll
    for (int mt = 0; mt < 8; ++mt) asm volatile("" : "+v"(acc[mt]));

    // validated packet load: retry until ALL 16 embedded tags == t (XCD-local)
    u64 a0[4], b0[4], a1[4], b1[4];
    {
      const u64* pb = pkt + (size_t)(t & 1) * 32768;
      const u32 et = (u32)t;
      for (;;) {
        bool ok = true;
#pragma unroll
        for (int kl = 0; kl < 4; ++kl) {
          const u64* p = pb + cb[kl];
          a0[kl] = __hip_atomic_load(p,      __ATOMIC_RELAXED, __HIP_MEMORY_SCOPE_AGENT);
          b0[kl] = __hip_atomic_load(p + 1,  __ATOMIC_RELAXED, __HIP_MEMORY_SCOPE_AGENT);
          a1[kl] = __hip_atomic_load(p + 16, __ATOMIC_RELAXED, __HIP_MEMORY_SCOPE_AGENT);
          b1[kl] = __hip_atomic_load(p + 17, __ATOMIC_RELAXED, __HIP_MEMORY_SCOPE_AGENT);
        }
#pragma unroll
        for (int kl = 0; kl < 4; ++kl) {
          ok = ok & ((u32)(a0[kl] >> 48) == et)
                  & (((u32)(b0[kl] >> 16) & 0xffffu) == et)
                  & ((u32)(a1[kl] >> 48) == et)
                  & (((u32)(b1[kl] >> 16) & 0xffffu) == et);
        }
        if (__all((int)ok)) break;
      }
    }
    asm volatile("" ::: "memory");

    // assemble h fragments: mt'=2q packet -> h[0..4), mt'=2q+1 -> h[4..8)
#pragma unroll
    for (int kl = 0; kl < 4; ++kl) {
      union { u32 u[4]; f16x8 v; } Bu;
      Bu.u[0] = (u32)a0[kl];
      Bu.u[1] = ((u32)(a0[kl] >> 32) & 0xffffu) | (((u32)b0[kl] & 0xffffu) << 16);
      Bu.u[2] = (u32)a1[kl];
      Bu.u[3] = ((u32)(a1[kl] >> 32) & 0xffffu) | (((u32)b1[kl] & 0xffffu) << 16);
      bfr[kl + 2] = Bu.v;
    }

#pragma unroll
    for (int kl = 2; kl < 6; ++kl)
#pragma unroll
      for (int mt = 0; mt < 8; ++mt)
        acc[mt] = __builtin_amdgcn_mfma_f32_16x16x32_f16(wfr[kl][mt], bfr[kl], acc[mt], 0, 0, 0);

#pragma unroll
    for (int mt = 0; mt < 8; ++mt)
      red[t & 1][(w * 8 + mt) * 64 + lane] = acc[mt];
    __syncthreads();                      // the ONLY barrier per step

    // ALL waves reduce: wave w owns mt-tile w. wv stride = 8*64 = 512 f32x4
    {
      const f32x4* rp2 = &red[t & 1][w * 64 + lane];
      f32x4 s01 = rp2[0]    + rp2[512];
      f32x4 s23 = rp2[1024] + rp2[1536];
      f32x4 s45 = rp2[2048] + rp2[2560];
      f32x4 s67 = rp2[3072] + rp2[3584];
      f32x4 s = (s01 + s23) + (s45 + s67);
      // lane owns all 4 gates of (b = bg0+b8, j = j0 + w*4 + q): i,f,g,o
      float gi = s.x + bias0, gf = s.y + bias1, gg = s.z + bias2, go = s.w + bias3;
      c_state = sigm(gf) * c_state + sigm(gi) * tanh_fast(gg);
      float h = sigm(go) * tanh_fast(c_state);

      // gather 4 q-values to q==0 lanes (2 shfl), fire tagged packet
      u32 hv  = (u32)__builtin_bit_cast(u16, (_Float16)h);
      u32 o16 = (u32)__shfl_xor((int)hv, 16);
      u32 pair = (hv & 0xffffu) | (o16 << 16);       // at even q: {h_q, h_q+1}
      u32 o32 = (u32)__shfl_xor((int)pair, 32);      // at q==0: {h2, h3}
      if (lane < 8) {                                // q==0 && n<8 (no dups)
        u64 tg = (u64)(u32)(t + 1);
        u64 Apkt = (u64)pair | ((u64)(o32 & 0xffffu) << 32) | (tg << 48);
        u64 Bpkt = (u64)((o32 >> 16) & 0xffffu) | (tg << 16);
        u64* pp = pkt + (size_t)((t + 1) & 1) * 32768 + pwb;
        __hip_atomic_store(pp,     Apkt, __ATOMIC_RELAXED, __HIP_MEMORY_SCOPE_AGENT);
        __hip_atomic_store(pp + 1, Bpkt, __ATOMIC_RELAXED, __HIP_MEMORY_SCOPE_AGENT);
      }
      // fused out-projection partial (fire-and-forget)
      float p = h * wout;
      p += __shfl_xor(p, 16);
      p += __shfl_xor(p, 32);
      if (lane < 8)
        __hip_atomic_fetch_add(&part[(((size_t)t * 8 + g) * 32 + r) * 8 + lane], p,
                               __ATOMIC_RELAXED, __HIP_MEMORY_SCOPE_WORKGROUP);
    }
  }
}

// ---------- K4: out[b][t] = b_out + sum_r part[t][g=b>>3][r][b&7] ----------
__global__ __launch_bounds__(256) void k_out(const float* __restrict__ part,
                                             const float* __restrict__ b_out,
                                             float* __restrict__ out) {
  int gi = blockIdx.x * 256 + threadIdx.x;      // 32768 threads
  int t = gi >> 6, b = gi & 63, g = b >> 3, b8 = b & 7;
  const float* p = part + (((size_t)t * 8 + g) * 32) * 8 + b8;
  float s = b_out[0];
#pragma unroll 8
  for (int r = 0; r < 32; ++r) s += p[r * 8];
  out[(size_t)b * 512 + t] = s;
}

extern "C" void kernel_launch(void* const* d_in, const int* in_sizes, int n_in,
                              void* d_out, int out_size, void* d_ws, size_t ws_size,
                              hipStream_t stream) {
  const float* x    = (const float*)d_in[0];
  const float* W_ih = (const float*)d_in[1];
  const float* W_hh = (const float*)d_in[2];
  const float* b_ih = (const float*)d_in[3];
  const float* b_hh = (const float*)d_in[4];
  const float* Wout = (const float*)d_in[5];
  const float* bout = (const float*)d_in[6];
  float* out = (float*)d_out;

  unsigned char* ws = (unsigned char*)d_ws;
  u16* xT   = (u16*)(ws + WS_XT_OFF);
  u16* Wf   = (u16*)(ws + WS_WF_OFF);
  u64* pkt  = (u64*)(ws + WS_PK_OFF);
  float* part = (float*)(ws + WS_WF_OFF);       // reuses Wf region after load

  k_init<<<128, 256, 0, stream>>>((uint4*)pkt);
  k_xpose<<<dim3(8, 8, 64), 256, 0, stream>>>(x, xT);
  k_wfrag<<<3072, 256, 0, stream>>>(W_ih, W_hh, Wf);

  void* args[7] = {&xT, &Wf, &pkt, &b_ih, &b_hh, &Wout, &part};
  hipLaunchCooperativeKernel((const void*)k_lstm, dim3(256), dim3(512), args, 0, stream);

  k_out<<<128, 256, 0, stream>>>(part, bout, out);
}